// Round 13
// baseline (165.286 us; speedup 1.0000x reference)
//
#include <hip/hip_runtime.h>
#include <hip/hip_bf16.h>
#include <cstdint>
#include <cstddef>
#include <climits>

// Problem constants (fixed by the reference)
constexpr int B_   = 2;
constexpr int NLR  = 8192;
constexpr int NHR  = 16384;
constexpr int CCH  = 32;    // feature channels
constexpr int NS   = 64;    // nsample
constexpr int THREADS = 256;
constexpr int BT   = 1024;  // k_build threads (single block)

// Spatial grid: hr coords span x in (0,10], y+40 in (0,10], z+3 in (0,20].
constexpr int GX = 11, GY = 11, GZ = 20;
constexpr int NCELLS = GX * GY * GZ;     // 2420 per batch
constexpr int NCT    = B_ * NCELLS;      // 4840 total
constexpr int CAP    = 192;              // per-query candidate cap (expected ~34)
constexpr float SCALE = 0.999f;

typedef __attribute__((ext_vector_type(8))) short bf16x8;
typedef __attribute__((ext_vector_type(4))) float f32x4;

// xyz = (float)i * vox + off + 0.5f*vox, all ops round-to-nearest f32 —
// must match the JAX/np reference bit-for-bit so d2 <= 1.0 never flips.
__device__ __forceinline__ float cvt_coord(int i, float vox, float off) {
    return __fadd_rn(__fadd_rn(__fmul_rn((float)i, vox), off), __fmul_rn(0.5f, vox));
}

__device__ __forceinline__ void hr_coords(const int* ip, float& x, float& y, float& z) {
    x = cvt_coord(ip[2], 0.05f,   0.0f);
    y = cvt_coord(ip[1], 0.05f, -40.0f);
    z = cvt_coord(ip[0], 0.1f,   -3.0f);
}

__device__ __forceinline__ int cell_of(float x, float y, float z) {
    const int cx = (int)(__fmul_rn(x, SCALE));
    const int cy = (int)(__fmul_rn(__fadd_rn(y, 40.0f), SCALE));
    const int cz = (int)(__fmul_rn(__fadd_rn(z,  3.0f), SCALE));
    return (cz * GY + cy) * GX + cx;
}

__device__ __forceinline__ unsigned short f2bf(float f) {
    __hip_bfloat16 h = __float2bfloat16(f);
    return __builtin_bit_cast(unsigned short, h);
}

// ---- K_BUILD: fused histogram + scan + scatter, ONE block of 1024 threads.
// Replaces memset + k_hist + k_scan + k_scatter (4 dispatches -> 1): the
// ~38us of small-kernel time + inter-dispatch gaps measured in r3-r8.
// Histogram and cursor live in LDS; per-thread cell ids cached in 32 VGPRs
// between the two passes. start[] (global) is what k_group consumes.
extern "C" __global__ void __launch_bounds__(BT)
k_build(const int* __restrict__ hr_idx, int* __restrict__ start,
        float4* __restrict__ pts)
{
    __shared__ int hist[NCT];      // histogram, then cursor (19.4 KB)
    __shared__ int sums[BT];       // scan partials (4 KB)
    const int t = threadIdx.x;

    for (int i = t; i < NCT; i += BT) hist[i] = 0;
    __syncthreads();

    // pass 1: histogram; cache cell ids in registers
    constexpr int PPT = B_ * NHR / BT;   // 32 points per thread
    int cellv[PPT];
#pragma unroll
    for (int it = 0; it < PPT; ++it) {
        const int gid = it * BT + t;               // coalesced 12B/thread
        const int bb  = gid >> 14;                 // NHR = 16384
        const int* ip = hr_idx + (size_t)gid * 3;
        float x, y, z;
        hr_coords(ip, x, y, z);
        const int c = bb * NCELLS + cell_of(x, y, z);
        cellv[it] = c;
        atomicAdd(&hist[c], 1);
    }
    __syncthreads();

    // exclusive scan (each hist slot read+overwritten by the same thread)
    constexpr int CH = (NCT + BT - 1) / BT;        // 5
    int loc[CH];
    int s = 0;
#pragma unroll
    for (int k = 0; k < CH; ++k) {
        const int i = t * CH + k;
        loc[k] = s;
        s += (i < NCT) ? hist[i] : 0;
    }
    sums[t] = s;
    __syncthreads();
    for (int off = 1; off < BT; off <<= 1) {
        const int v = (t >= off) ? sums[t - off] : 0;
        __syncthreads();
        sums[t] += v;
        __syncthreads();
    }
    const int pre = (t > 0) ? sums[t - 1] : 0;
#pragma unroll
    for (int k = 0; k < CH; ++k) {
        const int i = t * CH + k;
        if (i < NCT) {
            const int st = pre + loc[k];
            start[i] = st;     // global, for k_group
            hist[i]  = st;     // LDS cursor for pass 2
        }
    }
    if (t == BT - 1) start[NCT] = sums[BT - 1];    // total = B_*NHR
    __syncthreads();

    // pass 2: scatter (xyz recomputed from L2-warm hr_idx; exact same math)
#pragma unroll
    for (int it = 0; it < PPT; ++it) {
        const int gid = it * BT + t;
        const int* ip = hr_idx + (size_t)gid * 3;
        float x, y, z;
        hr_coords(ip, x, y, z);
        const int slot = atomicAdd(&hist[cellv[it]], 1);
        float4 v;
        v.x = x; v.y = y; v.z = z; v.w = __int_as_float(gid & (NHR - 1));
        pts[slot] = v;
    }
}

// ---- K_GROUP: ball query (grid) + MFMA MLP + max-pool; one wave per query.
// r9 change: Hb aliased onto Xf (same buffer XH) -> LDS 44->27.6 KB ->
// 5 blocks/CU (was 3) to hide gather latency (r8: VALU 30%, MFMA 3.5%,
// occupancy 24.8% == latency-bound). Aliasing is safe: DS ops execute
// in-order per wave, and all layer-1 Xf reads are issued before the
// post-MFMA Hb writes; layer-2 reads get compiler-inserted lgkmcnt.
extern "C" __global__ void __launch_bounds__(THREADS)
k_group(const int* __restrict__ lr_idx, const int* __restrict__ hr_idx,
        const float* __restrict__ lr_feat, const float* __restrict__ hr_feat,
        const float* __restrict__ W1, const float* __restrict__ b1,
        const float* __restrict__ W2, const float* __restrict__ b2,
        const int* __restrict__ start, const float4* __restrict__ pts,
        float* __restrict__ out)
{
    // block-shared pre-built B-fragments (weights), built once, synced once
    __shared__ __align__(16) unsigned short W1f[2][2][64][8]; // [ks][ct][lane][j]
    __shared__ __align__(16) unsigned short W2f[2][64][8];    // [ct][lane][j]
    // per-wave staging: X (input feats) then REUSED as Hb (layer-1 out)
    __shared__ __align__(16) unsigned short XH[4][64][32];    // swizzled rows
    __shared__ __align__(16) unsigned short XYZ[4][64][4];    // rel xyz bf16 (+pad)
    __shared__ int cand[4][CAP];

    const int tid  = threadIdx.x;
    const int wave = tid >> 6;
    const int lane = tid & 63;
    const int q    = blockIdx.x * 4 + wave;
    const int b    = q >> 13;

    // --- cooperative W-fragment build (logical k': 0..31 = feats = ref k+3;
    //     32..34 = xyz = ref k-32; >=35 = zero) ---
#pragma unroll
    for (int e = 0; e < 8; ++e) {
        const int flat = tid * 8 + e;                 // [0, 2048)
        const int j  = flat & 7;
        const int l  = (flat >> 3) & 63;
        const int ct = (flat >> 9) & 1;
        const int ks = (flat >> 10) & 1;
        const int kp = ks * 32 + (l >> 4) * 8 + j;    // logical k'
        const int n  = ct * 16 + (l & 15);
        float v = 0.0f;
        if (kp < 32)       v = W1[(kp + 3) * 32 + n];
        else if (kp < 35)  v = W1[(kp - 32) * 32 + n];
        W1f[ks][ct][l][j] = f2bf(v);
    }
#pragma unroll
    for (int e = 0; e < 4; ++e) {
        const int flat = tid * 4 + e;                 // [0, 1024)
        const int j  = flat & 7;
        const int l  = (flat >> 3) & 63;
        const int ct = (flat >> 9) & 1;
        const int k  = (l >> 4) * 8 + j;
        const int n  = ct * 16 + (l & 15);
        W2f[ct][l][j] = f2bf(W2[k * 32 + n]);
    }
    __syncthreads();   // only block-wide barrier; everything after is per-wave

    // --- query center ---
    const int* qip = lr_idx + (size_t)q * 3;
    const float qx = cvt_coord(qip[2], 0.4f,   0.0f);
    const float qy = cvt_coord(qip[1], 0.4f, -40.0f);
    const float qz = cvt_coord(qip[0], 1.0f,  -3.0f);

    const int cqx = (int)(__fmul_rn(qx, SCALE));
    const int cqy = (int)(__fmul_rn(__fadd_rn(qy, 40.0f), SCALE));
    const int cqz = (int)(__fmul_rn(__fadd_rn(qz,  3.0f), SCALE));
    const int x0 = max(cqx - 1, 0), x1 = min(cqx + 1, GX - 1);
    const int y0 = max(cqy - 1, 0), y1 = min(cqy + 1, GY - 1);
    const int z0 = max(cqz - 1, 0), z1 = min(cqz + 1, GZ - 1);
    const int nx = x1 - x0 + 1;
    const int bbase = b * NCELLS;

    // --- collect in-radius candidate ids (row-merged ranges; verified r3-r8) ---
    int cnt = 0;
    for (int zz = z0; zz <= z1; ++zz)
    for (int yy = y0; yy <= y1; ++yy) {
        const int g0 = bbase + (zz * GY + yy) * GX + x0;
        const int s  = start[g0];
        const int e  = start[g0 + nx];
        for (int base = s; base < e; base += 64) {
            const int j = base + lane;
            bool ok = false;
            int id = 0;
            if (j < e) {
                const float4 pv = pts[j];
                const float dx = __fsub_rn(qx, pv.x);
                const float dy = __fsub_rn(qy, pv.y);
                const float dz = __fsub_rn(qz, pv.z);
                const float d2 = __fadd_rn(__fadd_rn(__fmul_rn(dx, dx),
                                                     __fmul_rn(dy, dy)),
                                           __fmul_rn(dz, dz));
                ok = d2 <= 1.0f;
                id = __float_as_int(pv.w);
            }
            const unsigned long long m = __ballot(ok);
            if (m != 0ull) {
                const int before = (int)__popcll(m & ((1ull << lane) - 1ull));
                const int pos = cnt + before;
                if (ok && pos < CAP) cand[wave][pos] = id;
                cnt += (int)__popcll(m);
                if (cnt > CAP) cnt = CAP;
            }
        }
    }

    // --- per-lane neighbor assignment (reference top_k-by-lowest-index) ---
    int pid;
    if (cnt <= NS) {
        int myid = (lane < cnt) ? cand[wave][lane] : INT_MAX;
        int mp = myid;
#pragma unroll
        for (int s = 32; s >= 1; s >>= 1) mp = min(mp, __shfl_xor(mp, s, 64));
        pid = (lane < cnt) ? myid : ((cnt > 0) ? mp : 0);
    } else {
        const int c = cnt;
        int mine = 0;
        for (int k = 0; k < NS; ++k) {
            int lm = INT_MAX;
            for (int j = lane; j < c; j += 64) lm = min(lm, cand[wave][j]);
#pragma unroll
            for (int s = 32; s >= 1; s >>= 1) lm = min(lm, __shfl_xor(lm, s, 64));
            for (int j = lane; j < c; j += 64)
                if (cand[wave][j] == lm) cand[wave][j] = INT_MAX;
            if (lane == k) mine = lm;
        }
        pid = mine;
    }

    // --- gather neighbor row `lane` and stage to LDS (bf16) ---
    {
        const int* ip = hr_idx + ((size_t)b * NHR + pid) * 3;
        float px, py, pz;
        hr_coords(ip, px, py, pz);
        const int r = lane;
        ushort4 t;
        t.x = f2bf(__fsub_rn(px, qx));
        t.y = f2bf(__fsub_rn(py, qy));
        t.z = f2bf(__fsub_rn(pz, qz));
        t.w = 0;
        *reinterpret_cast<ushort4*>(&XYZ[wave][r][0]) = t;
        const float4* fp = reinterpret_cast<const float4*>(hr_feat + ((size_t)b * NHR + pid) * CCH);
#pragma unroll
        for (int c = 0; c < 4; ++c) {
            const float4 a = fp[2 * c];
            const float4 d = fp[2 * c + 1];
            uint4 u;
            u.x = (unsigned)f2bf(a.x) | ((unsigned)f2bf(a.y) << 16);
            u.y = (unsigned)f2bf(a.z) | ((unsigned)f2bf(a.w) << 16);
            u.z = (unsigned)f2bf(d.x) | ((unsigned)f2bf(d.y) << 16);
            u.w = (unsigned)f2bf(d.z) | ((unsigned)f2bf(d.w) << 16);
            const int byteoff = (c * 16) ^ ((r & 3) << 4);
            *reinterpret_cast<uint4*>(reinterpret_cast<char*>(&XH[wave][r][0]) + byteoff) = u;
        }
    }

    const int hi  = lane >> 4;
    const int c15 = lane & 15;

    // --- layer 1: H[64][32] = X[64][64] * W1p[64][32], 16 MFMA ---
    bf16x8 B1[2][2];
#pragma unroll
    for (int ks = 0; ks < 2; ++ks)
#pragma unroll
        for (int ct = 0; ct < 2; ++ct)
            B1[ks][ct] = *reinterpret_cast<const bf16x8*>(&W1f[ks][ct][lane][0]);

    const f32x4 zero4 = {0.0f, 0.0f, 0.0f, 0.0f};
    f32x4 acc[4][2];
#pragma unroll
    for (int rt = 0; rt < 4; ++rt) { acc[rt][0] = zero4; acc[rt][1] = zero4; }

#pragma unroll
    for (int rt = 0; rt < 4; ++rt) {
        const int row = rt * 16 + c15;
        const int byteoff = (hi * 16) ^ ((row & 3) << 4);
        const bf16x8 a0 = *reinterpret_cast<const bf16x8*>(
            reinterpret_cast<const char*>(&XH[wave][row][0]) + byteoff);
        bf16x8 a1 = {0, 0, 0, 0, 0, 0, 0, 0};
        if (hi == 0) {
            const ushort4 t = *reinterpret_cast<const ushort4*>(&XYZ[wave][row][0]);
            a1[0] = (short)t.x; a1[1] = (short)t.y; a1[2] = (short)t.z;
        }
#pragma unroll
        for (int ct = 0; ct < 2; ++ct) {
            acc[rt][ct] = __builtin_amdgcn_mfma_f32_16x16x32_bf16(a0, B1[0][ct], acc[rt][ct], 0, 0, 0);
            acc[rt][ct] = __builtin_amdgcn_mfma_f32_16x16x32_bf16(a1, B1[1][ct], acc[rt][ct], 0, 0, 0);
        }
    }

    // --- bias + relu + restage into XH (now Hb; same-wave DS in-order) ---
    const float bias1_0 = b1[c15];
    const float bias1_1 = b1[16 + c15];
#pragma unroll
    for (int rt = 0; rt < 4; ++rt)
#pragma unroll
        for (int ct = 0; ct < 2; ++ct) {
            const float bb = ct ? bias1_1 : bias1_0;
#pragma unroll
            for (int rr = 0; rr < 4; ++rr) {
                const float v = fmaxf(acc[rt][ct][rr] + bb, 0.0f);
                const int row = rt * 16 + hi * 4 + rr;
                const int boff = (ct * 32 + c15 * 2) ^ ((row & 3) << 4);
                *reinterpret_cast<unsigned short*>(
                    reinterpret_cast<char*>(&XH[wave][row][0]) + boff) = f2bf(v);
            }
        }

    // --- layer 2: H2[64][32] = Hb[64][32] * W2[32][32], 8 MFMA ---
    bf16x8 B2[2];
#pragma unroll
    for (int ct = 0; ct < 2; ++ct)
        B2[ct] = *reinterpret_cast<const bf16x8*>(&W2f[ct][lane][0]);

    f32x4 acc2[4][2];
#pragma unroll
    for (int rt = 0; rt < 4; ++rt) { acc2[rt][0] = zero4; acc2[rt][1] = zero4; }

#pragma unroll
    for (int rt = 0; rt < 4; ++rt) {
        const int row = rt * 16 + c15;
        const int byteoff = (hi * 16) ^ ((row & 3) << 4);
        const bf16x8 a = *reinterpret_cast<const bf16x8*>(
            reinterpret_cast<const char*>(&XH[wave][row][0]) + byteoff);
#pragma unroll
        for (int ct = 0; ct < 2; ++ct)
            acc2[rt][ct] = __builtin_amdgcn_mfma_f32_16x16x32_bf16(a, B2[ct], acc2[rt][ct], 0, 0, 0);
    }

    // --- bias + relu + max-pool over 64 rows ---
    const float bias2_0 = b2[c15];
    const float bias2_1 = b2[16 + c15];
    float m0 = 0.0f, m1 = 0.0f;    // relu output >= 0
#pragma unroll
    for (int rt = 0; rt < 4; ++rt)
#pragma unroll
        for (int rr = 0; rr < 4; ++rr) {
            m0 = fmaxf(m0, fmaxf(acc2[rt][0][rr] + bias2_0, 0.0f));
            m1 = fmaxf(m1, fmaxf(acc2[rt][1][rr] + bias2_1, 0.0f));
        }
    m0 = fmaxf(m0, __shfl_xor(m0, 16, 64));
    m0 = fmaxf(m0, __shfl_xor(m0, 32, 64));
    m1 = fmaxf(m1, __shfl_xor(m1, 16, 64));
    m1 = fmaxf(m1, __shfl_xor(m1, 32, 64));

    // --- write: out[q] = [lr_feat(32) | pooled(32)] ---
    float* orow = out + (size_t)q * (2 * CCH);
    if (lane < CCH)
        orow[lane] = lr_feat[(size_t)q * CCH + lane];
    if (lane < 16) {
        orow[CCH + lane]      = m0;
        orow[CCH + 16 + lane] = m1;
    }
}

extern "C" void kernel_launch(void* const* d_in, const int* in_sizes, int n_in,
                              void* d_out, int out_size, void* d_ws, size_t ws_size,
                              hipStream_t stream) {
    const int*   lr_idx  = (const int*)  d_in[0];
    const int*   hr_idx  = (const int*)  d_in[1];
    const float* lr_feat = (const float*)d_in[2];
    const float* hr_feat = (const float*)d_in[3];
    const float* W1      = (const float*)d_in[4];
    const float* b1      = (const float*)d_in[5];
    const float* W2      = (const float*)d_in[6];
    const float* b2      = (const float*)d_in[7];
    float* out = (float*)d_out;

    // workspace: start[NCT+1], then 16B-aligned pts[B_*NHR]
    int*    cell_start = (int*)d_ws;
    size_t  off = ((size_t)(NCT + 1) * sizeof(int) + 15) & ~(size_t)15;
    float4* pts = (float4*)((char*)d_ws + off);

    hipLaunchKernelGGL(k_build, dim3(1),             dim3(BT),      0, stream,
                       hr_idx, cell_start, pts);
    hipLaunchKernelGGL(k_group, dim3(B_ * NLR / 4),  dim3(THREADS), 0, stream,
                       lr_idx, hr_idx, lr_feat, hr_feat, W1, b1, W2, b2,
                       cell_start, pts, out);
}